// Round 1
// baseline (3501.443 us; speedup 1.0000x reference)
//
#include <hip/hip_runtime.h>
#include <cmath>

// Problem constants
static constexpr int kB   = 16;
static constexpr int kC   = 64;
static constexpr int kH   = 160;
static constexpr int kW   = 192;
static constexpr int kN   = 1000;
static constexpr int kAFC = 16;
static constexpr int kS   = 96;
static constexpr int kNC  = 2;
static constexpr int kD   = kAFC * kH;     // 2560
static constexpr int kHW  = kH * kW;       // 30720
static constexpr int kNM1 = kN - 1;        // 999
static constexpr int kM   = kB * kN;       // 16000
static constexpr int kRP  = kNC + 3 + 3 * kS; // 293
static constexpr int kK2  = 2 * kD;        // 5120

// d_out layout (floats)
static constexpr size_t OFF_RP   = 0;
static constexpr size_t OFF_ATTN = (size_t)kB * kN * kRP;          // 4,688,000
static constexpr size_t OFF_FEAT = OFF_ATTN + (size_t)kB * kN * kN; // 20,688,000

// ws layout (floats)
static constexpr size_t WS_BAF    = 0;                              // 40,960,000
static constexpr size_t WS_ATTF   = (size_t)kM * kD;                // 40,960,000
static constexpr size_t WS_SCORES = WS_ATTF + (size_t)kM * kD;      // 81,920,000
static constexpr size_t WS_FLAG   = WS_SCORES + (size_t)kM * kNM1;  // 97,904,000

// ---------------- mask dtype detection ----------------
// invalid_mask is a bool array in the reference; the harness may hand it to us
// as int32, uint8, or float32. Classify by byte pattern over the first
// 160000 bytes (safe to read under every interpretation).
__global__ void k_detect(const unsigned char* __restrict__ m, int* __restrict__ flag) {
  __shared__ int c1, c2, c3;
  if (threadIdx.x == 0) { c1 = 0; c2 = 0; c3 = 0; }
  __syncthreads();
  int l1 = 0, l2 = 0, l3 = 0;
  for (int g = threadIdx.x; g < (kN * kH) / 4; g += blockDim.x) {
    l1 += (m[4 * g + 1] != 0);
    l2 += (m[4 * g + 2] != 0);
    l3 += (m[4 * g + 3] != 0);
  }
  atomicAdd(&c1, l1); atomicAdd(&c2, l2); atomicAdd(&c3, l3);
  __syncthreads();
  if (threadIdx.x == 0) {
    int f;
    if (c1 > 0)            f = 1;  // uint8 bools
    else if (c2 | c3)      f = 2;  // float32 bools
    else                   f = 0;  // int32 bools
    *flag = f;
  }
}

// ---------------- 1x1 conv ----------------
__global__ __launch_bounds__(256) void k_conv(const float* __restrict__ bf,
                                              const float* __restrict__ cw,
                                              const float* __restrict__ cb,
                                              float* __restrict__ feats) {
  __shared__ float w[kAFC * kC];
  __shared__ float bsh[kAFC];
  for (int i = threadIdx.x; i < kAFC * kC; i += 256) w[i] = cw[i];
  if (threadIdx.x < kAFC) bsh[threadIdx.x] = cb[threadIdx.x];
  __syncthreads();
  int idx = blockIdx.x * 256 + threadIdx.x;
  if (idx >= kB * kHW) return;
  int b = idx / kHW, p = idx % kHW;
  float acc[kAFC];
#pragma unroll
  for (int o = 0; o < kAFC; o++) acc[o] = bsh[o];
  const float* src = bf + (size_t)b * kC * kHW + p;
#pragma unroll 4
  for (int c = 0; c < kC; c++) {
    float v = src[(size_t)c * kHW];
#pragma unroll
    for (int o = 0; o < kAFC; o++) acc[o] += v * w[o * kC + c];
  }
  float* dst = feats + (size_t)b * kAFC * kHW + p;
#pragma unroll
  for (int o = 0; o < kAFC; o++) dst[(size_t)o * kHW] = acc[o];
}

// ---------------- gather rois -> baf ----------------
// baf[b][n][a*H+h] = invalid(n,h) ? 0 : feats[b][a][h][cut_xs[n,h]]
__global__ __launch_bounds__(256) void k_gather(const float* __restrict__ feats,
                                                const int* __restrict__ cut,
                                                const void* __restrict__ mask,
                                                const int* __restrict__ flag,
                                                float* __restrict__ baf) {
  int idx = blockIdx.x * 256 + threadIdx.x;
  if (idx >= kB * kN * kH) return;
  int b = idx / (kN * kH);
  int r = idx % (kN * kH);
  int n = r / kH, h = r % kH;
  int f = *flag;
  bool inv;
  if (f == 0)      inv = ((const int*)mask)[r] != 0;
  else if (f == 1) inv = ((const unsigned char*)mask)[r] != 0;
  else             inv = ((const float*)mask)[r] != 0.0f;
  int x = cut[r];
  float* dst = baf + (size_t)(b * kN + n) * kD + h;
  if (inv) {
#pragma unroll
    for (int a = 0; a < kAFC; a++) dst[a * kH] = 0.0f;
  } else {
    const float* sp = feats + (size_t)b * kAFC * kHW + (size_t)h * kW + x;
#pragma unroll
    for (int a = 0; a < kAFC; a++) dst[a * kH] = sp[(size_t)a * kHW];
  }
}

// ---------------- GEMM 1: scores = baf @ attn_w^T + attn_b ----------------
// A: (16000 x 2560) row-major, Bt: (999 x 2560) row-major, C: (16000 x 999)
__global__ __launch_bounds__(256) void k_gemm_scores(const float* __restrict__ A,
                                                     const float* __restrict__ Bt,
                                                     const float* __restrict__ bias,
                                                     float* __restrict__ C) {
  __shared__ float As[16][68];
  __shared__ float Bs[16][68];
  int tid = threadIdx.x;
  int m0 = blockIdx.x * 64, j0 = blockIdx.y * 64;
  int lr = tid >> 2;            // 0..63
  int lk = (tid & 3) * 4;       // 0,4,8,12
  int ty = tid >> 4, tx = tid & 15;
  float acc[4][4] = {};
  for (int k0 = 0; k0 < kD; k0 += 16) {
    float4 av = *(const float4*)(A + (size_t)(m0 + lr) * kD + k0 + lk);
    float4 bv = make_float4(0.f, 0.f, 0.f, 0.f);
    int j = j0 + lr;
    if (j < kNM1) bv = *(const float4*)(Bt + (size_t)j * kD + k0 + lk);
    As[lk + 0][lr] = av.x; As[lk + 1][lr] = av.y; As[lk + 2][lr] = av.z; As[lk + 3][lr] = av.w;
    Bs[lk + 0][lr] = bv.x; Bs[lk + 1][lr] = bv.y; Bs[lk + 2][lr] = bv.z; Bs[lk + 3][lr] = bv.w;
    __syncthreads();
#pragma unroll
    for (int k = 0; k < 16; k++) {
      float4 a4 = *(const float4*)&As[k][ty * 4];
      float4 b4 = *(const float4*)&Bs[k][tx * 4];
      float avv[4] = {a4.x, a4.y, a4.z, a4.w};
      float bvv[4] = {b4.x, b4.y, b4.z, b4.w};
#pragma unroll
      for (int i = 0; i < 4; i++)
#pragma unroll
        for (int jj = 0; jj < 4; jj++) acc[i][jj] += avv[i] * bvv[jj];
    }
    __syncthreads();
  }
#pragma unroll
  for (int i = 0; i < 4; i++) {
    int m = m0 + ty * 4 + i;
#pragma unroll
    for (int jj = 0; jj < 4; jj++) {
      int j = j0 + tx * 4 + jj;
      if (j < kNM1) C[(size_t)m * kNM1 + j] = acc[i][jj] + bias[j];
    }
  }
}

// ---------------- softmax + expand into attn_mat (+anchor cols 2..4) --------
__global__ __launch_bounds__(256) void k_softmax(const float* __restrict__ scores,
                                                 const float* __restrict__ anchors,
                                                 float* __restrict__ attn_out,
                                                 float* __restrict__ rp) {
  int m = blockIdx.x;           // 0..15999
  int i = m % kN;
  const float* srow = scores + (size_t)m * kNM1;
  int tid = threadIdx.x;
  __shared__ float red[4];
  float v[4];
  float mx = -INFINITY;
#pragma unroll
  for (int t = 0; t < 4; t++) {
    int j = tid + t * 256;
    v[t] = (j < kNM1) ? srow[j] : -INFINITY;
    mx = fmaxf(mx, v[t]);
  }
#pragma unroll
  for (int o = 32; o; o >>= 1) mx = fmaxf(mx, __shfl_down(mx, o));
  if ((tid & 63) == 0) red[tid >> 6] = mx;
  __syncthreads();
  mx = fmaxf(fmaxf(red[0], red[1]), fmaxf(red[2], red[3]));
  __syncthreads();
  float s = 0.f;
#pragma unroll
  for (int t = 0; t < 4; t++) {
    int j = tid + t * 256;
    v[t] = (j < kNM1) ? __expf(v[t] - mx) : 0.f;
    s += v[t];
  }
#pragma unroll
  for (int o = 32; o; o >>= 1) s += __shfl_down(s, o);
  if ((tid & 63) == 0) red[tid >> 6] = s;
  __syncthreads();
  s = red[0] + red[1] + red[2] + red[3];
  float inv = 1.0f / s;
  float* orow = attn_out + (size_t)m * kN;
#pragma unroll
  for (int t = 0; t < 4; t++) {
    int j = tid + t * 256;
    if (j < kNM1) {
      int dst = j + (j >= i);
      orow[dst] = v[t] * inv;
    }
  }
  if (tid == 0) orow[i] = 0.f;
  if (tid < 3) rp[(size_t)m * kRP + 2 + tid] = anchors[(size_t)i * kRP + 2 + tid];
}

// ---------------- GEMM 2 (batched NN): att_feats = attn_mat @ baf -----------
// per b: A (1000x1000) row-major, Bv (1000x2560) row-major, C (1000x2560)
__global__ __launch_bounds__(256) void k_gemm_att(const float* __restrict__ attn,
                                                  const float* __restrict__ baf,
                                                  float* __restrict__ attf) {
  int b = blockIdx.z;
  const float* A  = attn + (size_t)b * kN * kN;
  const float* Bv = baf  + (size_t)b * kN * kD;
  float* C        = attf + (size_t)b * kN * kD;
  __shared__ float As[16][68];
  __shared__ float Bs[16][68];
  int tid = threadIdx.x;
  int m0 = blockIdx.x * 64, j0 = blockIdx.y * 64;
  int lr = tid >> 2;
  int lk = (tid & 3) * 4;
  int bk = tid >> 4;            // 0..15  (B tile k-row)
  int bq = (tid & 15) * 4;      // 0..60  (B tile col quad)
  int ty = tid >> 4, tx = tid & 15;
  float acc[4][4] = {};
  for (int k0 = 0; k0 < kN; k0 += 16) {
    // A tile (transposed store), guards on m and k
    float a4[4];
    int mrow = m0 + lr;
#pragma unroll
    for (int q = 0; q < 4; q++) {
      int k = k0 + lk + q;
      a4[q] = (mrow < kN && k < kN) ? A[(size_t)mrow * kN + k] : 0.f;
    }
    As[lk + 0][lr] = a4[0]; As[lk + 1][lr] = a4[1]; As[lk + 2][lr] = a4[2]; As[lk + 3][lr] = a4[3];
    // B tile (direct store)
    int kb = k0 + bk;
    float4 bv = make_float4(0.f, 0.f, 0.f, 0.f);
    if (kb < kN) bv = *(const float4*)(Bv + (size_t)kb * kD + j0 + bq);
    *(float4*)&Bs[bk][bq] = bv;
    __syncthreads();
#pragma unroll
    for (int k = 0; k < 16; k++) {
      float4 a4v = *(const float4*)&As[k][ty * 4];
      float4 b4v = *(const float4*)&Bs[k][tx * 4];
      float avv[4] = {a4v.x, a4v.y, a4v.z, a4v.w};
      float bvv[4] = {b4v.x, b4v.y, b4v.z, b4v.w};
#pragma unroll
      for (int i = 0; i < 4; i++)
#pragma unroll
        for (int jj = 0; jj < 4; jj++) acc[i][jj] += avv[i] * bvv[jj];
    }
    __syncthreads();
  }
#pragma unroll
  for (int i = 0; i < 4; i++) {
    int mrow = m0 + ty * 4 + i;
    if (mrow < kN) {
#pragma unroll
      for (int jj = 0; jj < 4; jj++) {
        int j = j0 + tx * 4 + jj;
        C[(size_t)mrow * kD + j] = acc[i][jj];
      }
    }
  }
}

// ---------------- GEMM 3: head = [att_feats | baf] @ [reg_w;cls_w]^T --------
// + bias, sigmoid on reg cols 192..287, add anchors, scatter into reg_proposals
__global__ __launch_bounds__(256) void k_gemm_head(const float* __restrict__ attf,
                                                   const float* __restrict__ baf,
                                                   const float* __restrict__ reg_w,
                                                   const float* __restrict__ cls_w,
                                                   const float* __restrict__ reg_b,
                                                   const float* __restrict__ cls_b,
                                                   const float* __restrict__ anchors,
                                                   float* __restrict__ rp) {
  __shared__ float As[16][68];
  __shared__ float Bs[16][68];
  int tid = threadIdx.x;
  int m0 = blockIdx.x * 64, j0 = blockIdx.y * 64;
  int lr = tid >> 2;
  int lk = (tid & 3) * 4;
  int ty = tid >> 4, tx = tid & 15;
  float acc[4][4] = {};
  for (int k0 = 0; k0 < kK2; k0 += 16) {
    const float* Ap = (k0 < kD) ? (attf + (size_t)(m0 + lr) * kD + k0 + lk)
                                : (baf  + (size_t)(m0 + lr) * kD + (k0 - kD) + lk);
    float4 av = *(const float4*)Ap;
    int j = j0 + lr;
    float4 bv = make_float4(0.f, 0.f, 0.f, 0.f);
    if (j < 3 * kS)             bv = *(const float4*)(reg_w + (size_t)j * kK2 + k0 + lk);
    else if (j < 3 * kS + kNC)  bv = *(const float4*)(cls_w + (size_t)(j - 3 * kS) * kK2 + k0 + lk);
    As[lk + 0][lr] = av.x; As[lk + 1][lr] = av.y; As[lk + 2][lr] = av.z; As[lk + 3][lr] = av.w;
    Bs[lk + 0][lr] = bv.x; Bs[lk + 1][lr] = bv.y; Bs[lk + 2][lr] = bv.z; Bs[lk + 3][lr] = bv.w;
    __syncthreads();
#pragma unroll
    for (int k = 0; k < 16; k++) {
      float4 a4 = *(const float4*)&As[k][ty * 4];
      float4 b4 = *(const float4*)&Bs[k][tx * 4];
      float avv[4] = {a4.x, a4.y, a4.z, a4.w};
      float bvv[4] = {b4.x, b4.y, b4.z, b4.w};
#pragma unroll
      for (int i = 0; i < 4; i++)
#pragma unroll
        for (int jj = 0; jj < 4; jj++) acc[i][jj] += avv[i] * bvv[jj];
    }
    __syncthreads();
  }
#pragma unroll
  for (int i = 0; i < 4; i++) {
    int m = m0 + ty * 4 + i;
    int n = m % kN;
#pragma unroll
    for (int jj = 0; jj < 4; jj++) {
      int j = j0 + tx * 4 + jj;
      if (j < 3 * kS) {
        float v = acc[i][jj] + reg_b[j];
        if (j >= 2 * kS) v = 1.0f / (1.0f + expf(-v));
        rp[(size_t)m * kRP + 5 + j] = anchors[(size_t)n * kRP + 5 + j] + v;
      } else if (j < 3 * kS + kNC) {
        rp[(size_t)m * kRP + (j - 3 * kS)] = acc[i][jj] + cls_b[j - 3 * kS];
      }
    }
  }
}

extern "C" void kernel_launch(void* const* d_in, const int* in_sizes, int n_in,
                              void* d_out, int out_size, void* d_ws, size_t ws_size,
                              hipStream_t stream) {
  const float* bf      = (const float*)d_in[0];
  const float* conv_w  = (const float*)d_in[1];
  const float* conv_b  = (const float*)d_in[2];
  const int*   cut     = (const int*)d_in[3];
  const void*  mask    = d_in[4];
  const float* anchors = (const float*)d_in[5];
  const float* attn_w  = (const float*)d_in[6];
  const float* attn_b  = (const float*)d_in[7];
  const float* cls_w   = (const float*)d_in[8];
  const float* cls_b   = (const float*)d_in[9];
  const float* reg_w   = (const float*)d_in[10];
  const float* reg_b   = (const float*)d_in[11];

  float* out     = (float*)d_out;
  float* rp      = out + OFF_RP;
  float* attn_o  = out + OFF_ATTN;
  float* feats   = out + OFF_FEAT;

  float* ws      = (float*)d_ws;
  float* baf     = ws + WS_BAF;
  float* attf    = ws + WS_ATTF;
  float* scores  = ws + WS_SCORES;
  int*   flag    = (int*)(ws + WS_FLAG);

  k_detect<<<1, 256, 0, stream>>>((const unsigned char*)mask, flag);
  k_conv<<<(kB * kHW) / 256, 256, 0, stream>>>(bf, conv_w, conv_b, feats);
  k_gather<<<(kB * kN * kH) / 256, 256, 0, stream>>>(feats, cut, mask, flag, baf);
  {
    dim3 g(kM / 64, (kNM1 + 63) / 64);
    k_gemm_scores<<<g, 256, 0, stream>>>(baf, attn_w, attn_b, scores);
  }
  k_softmax<<<kM, 256, 0, stream>>>(scores, anchors, attn_o, rp);
  {
    dim3 g((kN + 63) / 64, kD / 64, kB);
    k_gemm_att<<<g, 256, 0, stream>>>(attn_o, baf, attf);
  }
  {
    dim3 g(kM / 64, (3 * kS + kNC + 63) / 64);
    k_gemm_head<<<g, 256, 0, stream>>>(attf, baf, reg_w, cls_w, reg_b, cls_b, anchors, rp);
  }
}

// Round 2
// 830.795 us; speedup vs baseline: 4.2146x; 4.2146x over previous
//
#include <hip/hip_runtime.h>
#include <cmath>

// Problem constants
static constexpr int kB   = 16;
static constexpr int kC   = 64;
static constexpr int kH   = 160;
static constexpr int kW   = 192;
static constexpr int kN   = 1000;
static constexpr int kAFC = 16;
static constexpr int kS   = 96;
static constexpr int kNC  = 2;
static constexpr int kD   = kAFC * kH;     // 2560
static constexpr int kHW  = kH * kW;       // 30720
static constexpr int kNM1 = kN - 1;        // 999
static constexpr int kM   = kB * kN;       // 16000
static constexpr int kRP  = kNC + 3 + 3 * kS; // 293
static constexpr int kK2  = 2 * kD;        // 5120
static constexpr int kNP  = 1024;          // padded N for att GEMM

// d_out layout (floats)
static constexpr size_t OFF_RP   = 0;
static constexpr size_t OFF_ATTN = (size_t)kB * kN * kRP;
static constexpr size_t OFF_FEAT = OFF_ATTN + (size_t)kB * kN * kN;

// ws layout (bytes)
static constexpr size_t WB_BAF   = 0;                                    // bf16 [16000][2560]
static constexpr size_t WB_BAFT  = WB_BAF   + (size_t)kM * kD * 2;       // bf16 [16][2560][1024]
static constexpr size_t WB_ATTF  = WB_BAFT  + (size_t)kB * kD * kNP * 2; // bf16 [16000][2560]
static constexpr size_t WB_ATTNB = WB_ATTF  + (size_t)kM * kD * 2;       // bf16 [16][1024][1024]
static constexpr size_t WB_SCORE = WB_ATTNB + (size_t)kB * kNP * kNP * 2;// f32  [16000][999]
static constexpr size_t WB_ATTNW = WB_SCORE + (size_t)kM * kNM1 * 4;     // bf16 [1024][2560]
static constexpr size_t WB_WHEAD = WB_ATTNW + (size_t)kNP * kD * 2;      // bf16 [384][5120]
static constexpr size_t WB_FLAG  = WB_WHEAD + (size_t)384 * kK2 * 2;     // int

typedef __attribute__((ext_vector_type(8))) short bf16x8;
typedef __attribute__((ext_vector_type(4))) float f32x4;

static __device__ inline short f2bf(float f) {
  union { float f; unsigned u; } x; x.f = f;
  unsigned r = (x.u + 0x7FFFu + ((x.u >> 16) & 1u)) >> 16;
  return (short)r;
}

#define GLOAD_LDS16(gp, lp) __builtin_amdgcn_global_load_lds( \
    (const __attribute__((address_space(1))) void*)(gp),      \
    (__attribute__((address_space(3))) void*)(lp), 16, 0, 0)

// ---------------- mask dtype detection ----------------
__global__ void k_detect(const unsigned char* __restrict__ m, int* __restrict__ flag) {
  __shared__ int c1, c2, c3;
  if (threadIdx.x == 0) { c1 = 0; c2 = 0; c3 = 0; }
  __syncthreads();
  int l1 = 0, l2 = 0, l3 = 0;
  for (int g = threadIdx.x; g < (kN * kH) / 4; g += blockDim.x) {
    l1 += (m[4 * g + 1] != 0);
    l2 += (m[4 * g + 2] != 0);
    l3 += (m[4 * g + 3] != 0);
  }
  atomicAdd(&c1, l1); atomicAdd(&c2, l2); atomicAdd(&c3, l3);
  __syncthreads();
  if (threadIdx.x == 0) {
    int f;
    if (c1 > 0)            f = 1;  // uint8 bools
    else if (c2 | c3)      f = 2;  // float32 bools
    else                   f = 0;  // int32 bools
    *flag = f;
  }
}

// ---------------- 1x1 conv (fp32, feats is an output) ----------------
__global__ __launch_bounds__(256) void k_conv(const float* __restrict__ bf,
                                              const float* __restrict__ cw,
                                              const float* __restrict__ cb,
                                              float* __restrict__ feats) {
  __shared__ float w[kAFC * kC];
  __shared__ float bsh[kAFC];
  for (int i = threadIdx.x; i < kAFC * kC; i += 256) w[i] = cw[i];
  if (threadIdx.x < kAFC) bsh[threadIdx.x] = cb[threadIdx.x];
  __syncthreads();
  int idx = blockIdx.x * 256 + threadIdx.x;
  if (idx >= kB * kHW) return;
  int b = idx / kHW, p = idx % kHW;
  float acc[kAFC];
#pragma unroll
  for (int o = 0; o < kAFC; o++) acc[o] = bsh[o];
  const float* src = bf + (size_t)b * kC * kHW + p;
#pragma unroll 4
  for (int c = 0; c < kC; c++) {
    float v = src[(size_t)c * kHW];
#pragma unroll
    for (int o = 0; o < kAFC; o++) acc[o] += v * w[o * kC + c];
  }
  float* dst = feats + (size_t)b * kAFC * kHW + p;
#pragma unroll
  for (int o = 0; o < kAFC; o++) dst[(size_t)o * kHW] = acc[o];
}

// ---------------- gather rois -> baf (bf16) ----------------
__global__ __launch_bounds__(256) void k_gather(const float* __restrict__ feats,
                                                const int* __restrict__ cut,
                                                const void* __restrict__ mask,
                                                const int* __restrict__ flag,
                                                short* __restrict__ baf) {
  int idx = blockIdx.x * 256 + threadIdx.x;
  if (idx >= kB * kN * kH) return;
  int b = idx / (kN * kH);
  int r = idx % (kN * kH);
  int n = r / kH, h = r % kH;
  int f = *flag;
  bool inv;
  if (f == 0)      inv = ((const int*)mask)[r] != 0;
  else if (f == 1) inv = ((const unsigned char*)mask)[r] != 0;
  else             inv = ((const float*)mask)[r] != 0.0f;
  int x = cut[r];
  short* dst = baf + (size_t)(b * kN + n) * kD + h;
  if (inv) {
#pragma unroll
    for (int a = 0; a < kAFC; a++) dst[a * kH] = 0;
  } else {
    const float* sp = feats + (size_t)b * kAFC * kHW + (size_t)h * kW + x;
#pragma unroll
    for (int a = 0; a < kAFC; a++) dst[a * kH] = f2bf(sp[(size_t)a * kHW]);
  }
}

// ---------------- transpose baf -> bafT [b][d][n_pad] (zero-pad n>=1000) ----
__global__ __launch_bounds__(256) void k_transpose(const short* __restrict__ baf,
                                                   short* __restrict__ bafT) {
  __shared__ short t[64][66];
  int b = blockIdx.z, n0 = blockIdx.y * 64, d0 = blockIdx.x * 64;
  int c = threadIdx.x & 63, r4 = threadIdx.x >> 6;  // c: 0..63, r4: 0..3
#pragma unroll
  for (int i = 0; i < 16; i++) {
    int nl = r4 + i * 4;
    int n = n0 + nl;
    short v = (n < kN) ? baf[(size_t)(b * kN + n) * kD + d0 + c] : (short)0;
    t[nl][c] = v;
  }
  __syncthreads();
#pragma unroll
  for (int i = 0; i < 16; i++) {
    int dl = r4 + i * 4;
    bafT[((size_t)b * kD + d0 + dl) * kNP + n0 + c] = t[c][dl];
  }
}

// ---------------- convert attn_w -> bf16 [1024][2560] (pad rows) ------------
__global__ __launch_bounds__(256) void k_cvt_attnw(const float* __restrict__ w,
                                                   short* __restrict__ o) {
  int idx = blockIdx.x * 256 + threadIdx.x;
  if (idx >= kNP * kD) return;
  int j = idx / kD;
  o[idx] = (j < kNM1) ? f2bf(w[idx]) : (short)0;
}

// ---------------- build head weight bf16 [384][5120] ------------------------
__global__ __launch_bounds__(256) void k_cvt_whead(const float* __restrict__ reg_w,
                                                   const float* __restrict__ cls_w,
                                                   short* __restrict__ o) {
  int idx = blockIdx.x * 256 + threadIdx.x;
  if (idx >= 384 * kK2) return;
  int j = idx / kK2, k = idx % kK2;
  float v = 0.f;
  if (j < 3 * kS)            v = reg_w[idx];
  else if (j < 3 * kS + kNC) v = cls_w[(size_t)(j - 3 * kS) * kK2 + k];
  o[idx] = f2bf(v);
}

// ---------------- softmax: scores -> attn_mat (f32 out) + attn bf16 padded --
__global__ __launch_bounds__(256) void k_softmax(const float* __restrict__ scores,
                                                 const float* __restrict__ anchors,
                                                 float* __restrict__ attn_out,
                                                 short* __restrict__ attn_bf,
                                                 float* __restrict__ rp) {
  int m = blockIdx.x;           // 0..15999
  int b = m / kN;
  int i = m % kN;
  const float* srow = scores + (size_t)m * kNM1;
  int tid = threadIdx.x;
  __shared__ float red[4];
  float v[4];
  float mx = -INFINITY;
#pragma unroll
  for (int t = 0; t < 4; t++) {
    int j = tid + t * 256;
    v[t] = (j < kNM1) ? srow[j] : -INFINITY;
    mx = fmaxf(mx, v[t]);
  }
#pragma unroll
  for (int o = 32; o; o >>= 1) mx = fmaxf(mx, __shfl_down(mx, o));
  if ((tid & 63) == 0) red[tid >> 6] = mx;
  __syncthreads();
  mx = fmaxf(fmaxf(red[0], red[1]), fmaxf(red[2], red[3]));
  __syncthreads();
  float s = 0.f;
#pragma unroll
  for (int t = 0; t < 4; t++) {
    int j = tid + t * 256;
    v[t] = (j < kNM1) ? __expf(v[t] - mx) : 0.f;
    s += v[t];
  }
#pragma unroll
  for (int o = 32; o; o >>= 1) s += __shfl_down(s, o);
  if ((tid & 63) == 0) red[tid >> 6] = s;
  __syncthreads();
  s = red[0] + red[1] + red[2] + red[3];
  float inv = 1.0f / s;
  float* orow = attn_out + (size_t)m * kN;
  short* brow = attn_bf + ((size_t)b * kNP + i) * kNP;
#pragma unroll
  for (int t = 0; t < 4; t++) {
    int j = tid + t * 256;
    if (j < kNM1) {
      int dst = j + (j >= i);
      float p = v[t] * inv;
      orow[dst] = p;
      brow[dst] = f2bf(p);
    }
  }
  if (tid == 0) { orow[i] = 0.f; brow[i] = 0; }
  if (tid < kNP - kN) brow[kN + tid] = 0;           // pad cols 1000..1023
  if (tid < 3) rp[(size_t)m * kRP + 2 + tid] = anchors[(size_t)i * kRP + 2 + tid];
}

// ---------------- MFMA bf16 GEMM, m97 structure (128x128 tile, BK=32) -------
// MODE 0: scores = baf @ attnw^T (+attn_b), f32 out [16000][999]
// MODE 1: attf   = attn @ bafT^T, bf16 out [16][1000][2560], batched over z
// MODE 2: head   = [attf|baf] @ whead^T, epilogue -> rp
template <int MODE>
__global__ __launch_bounds__(256) void k_mfma_gemm(
    const short* __restrict__ A, const short* __restrict__ A2,
    const short* __restrict__ Bt,
    const float* __restrict__ bias, const float* __restrict__ bias2,
    const float* __restrict__ anchors,
    void* __restrict__ Cout, int K, int lda, int ldb) {
  __shared__ short smem[8192];                 // As: 8 KB, Bs: 8 KB
  char* sA = (char*)smem;
  char* sB = (char*)smem + 8192;
  int tid = threadIdx.x, lane = tid & 63, wv = tid >> 6;
  int m0 = blockIdx.x * 128, n0 = blockIdx.y * 128;
  const short* Ap = A;
  const short* Bp = Bt;
  int bz = 0;
  if (MODE == 1) {
    bz = blockIdx.z;
    Ap = A + (size_t)bz * kNP * kNP;
    Bp = Bt + (size_t)bz * kD * kNP;
  }
  int wm = (wv >> 1) * 64, wn = (wv & 1) * 64;
  int sRow = lane >> 2;          // 0..15 row within 16-row chunk
  int sKo  = (lane & 3) * 8;     // k element offset
  f32x4 acc[4][4] = {};

  for (int k0 = 0; k0 < K; k0 += 32) {
    const short* Abase = Ap;
    int kk = k0;
    if (MODE == 2 && k0 >= kD) { Abase = A2; kk = k0 - kD; }
    const short* ga = Abase + (size_t)(m0 + 32 * wv + sRow) * lda + kk + sKo;
    GLOAD_LDS16(ga,            sA + wv * 2048);
    GLOAD_LDS16(ga + 16 * lda, sA + wv * 2048 + 1024);
    const short* gb = Bp + (size_t)(n0 + 32 * wv + sRow) * ldb + k0 + sKo;
    GLOAD_LDS16(gb,            sB + wv * 2048);
    GLOAD_LDS16(gb + 16 * ldb, sB + wv * 2048 + 1024);
    __syncthreads();

    bf16x8 af[4], bfg[4];
#pragma unroll
    for (int i = 0; i < 4; i++)
      af[i] = *(const bf16x8*)(sA + ((size_t)(wm + i * 16 + (lane & 15))) * 64 + (lane >> 4) * 16);
#pragma unroll
    for (int j = 0; j < 4; j++)
      bfg[j] = *(const bf16x8*)(sB + ((size_t)(wn + j * 16 + (lane & 15))) * 64 + (lane >> 4) * 16);
#pragma unroll
    for (int i = 0; i < 4; i++)
#pragma unroll
      for (int j = 0; j < 4; j++)
        acc[i][j] = __builtin_amdgcn_mfma_f32_16x16x32_bf16(af[i], bfg[j], acc[i][j], 0, 0, 0);
    __syncthreads();
  }

  // epilogue
#pragma unroll
  for (int i = 0; i < 4; i++) {
#pragma unroll
    for (int j = 0; j < 4; j++) {
#pragma unroll
      for (int r = 0; r < 4; r++) {
        int row = m0 + wm + i * 16 + (lane >> 4) * 4 + r;
        int col = n0 + wn + j * 16 + (lane & 15);
        float v = acc[i][j][r];
        if (MODE == 0) {
          if (col < kNM1)
            ((float*)Cout)[(size_t)row * kNM1 + col] = v + bias[col];
        } else if (MODE == 1) {
          if (row < kN)
            ((short*)Cout)[((size_t)bz * kN + row) * kD + col] = f2bf(v);
        } else {
          float* rp = (float*)Cout;
          int n = row % kN;
          if (col < 3 * kS) {
            float t = v + bias[col];
            if (col >= 2 * kS) t = 1.0f / (1.0f + __expf(-t));
            rp[(size_t)row * kRP + 5 + col] = anchors[(size_t)n * kRP + 5 + col] + t;
          } else if (col < 3 * kS + kNC) {
            rp[(size_t)row * kRP + (col - 3 * kS)] = v + bias2[col - 3 * kS];
          }
        }
      }
    }
  }
}

extern "C" void kernel_launch(void* const* d_in, const int* in_sizes, int n_in,
                              void* d_out, int out_size, void* d_ws, size_t ws_size,
                              hipStream_t stream) {
  const float* bf      = (const float*)d_in[0];
  const float* conv_w  = (const float*)d_in[1];
  const float* conv_b  = (const float*)d_in[2];
  const int*   cut     = (const int*)d_in[3];
  const void*  mask    = d_in[4];
  const float* anchors = (const float*)d_in[5];
  const float* attn_w  = (const float*)d_in[6];
  const float* attn_b  = (const float*)d_in[7];
  const float* cls_w   = (const float*)d_in[8];
  const float* cls_b   = (const float*)d_in[9];
  const float* reg_w   = (const float*)d_in[10];
  const float* reg_b   = (const float*)d_in[11];

  float* out    = (float*)d_out;
  float* rp     = out + OFF_RP;
  float* attn_o = out + OFF_ATTN;
  float* feats  = out + OFF_FEAT;

  char*  ws      = (char*)d_ws;
  short* baf     = (short*)(ws + WB_BAF);
  short* bafT    = (short*)(ws + WB_BAFT);
  short* attf    = (short*)(ws + WB_ATTF);
  short* attn_bf = (short*)(ws + WB_ATTNB);
  float* scores  = (float*)(ws + WB_SCORE);
  short* attnw   = (short*)(ws + WB_ATTNW);
  short* whead   = (short*)(ws + WB_WHEAD);
  int*   flag    = (int*)(ws + WB_FLAG);

  k_detect<<<1, 256, 0, stream>>>((const unsigned char*)mask, flag);
  k_conv<<<(kB * kHW) / 256, 256, 0, stream>>>(bf, conv_w, conv_b, feats);
  k_gather<<<(kB * kN * kH) / 256, 256, 0, stream>>>(feats, cut, mask, flag, baf);
  {
    dim3 g(kD / 64, 16, kB);  // d-tiles, n-tiles, batch
    k_transpose<<<g, 256, 0, stream>>>(baf, bafT);
  }
  k_cvt_attnw<<<(kNP * kD + 255) / 256, 256, 0, stream>>>(attn_w, attnw);
  k_cvt_whead<<<(384 * kK2 + 255) / 256, 256, 0, stream>>>(reg_w, cls_w, whead);
  {
    dim3 g(kM / 128, 8);      // 125 x 8 (cols padded to 1024)
    k_mfma_gemm<0><<<g, 256, 0, stream>>>(baf, nullptr, attnw, attn_b, nullptr,
                                          nullptr, scores, kD, kD, kD);
  }
  k_softmax<<<kM, 256, 0, stream>>>(scores, anchors, attn_o, attn_bf, rp);
  {
    dim3 g(kNP / 128, kD / 128, kB);  // 8 x 20 x 16
    k_mfma_gemm<1><<<g, 256, 0, stream>>>(attn_bf, nullptr, bafT, nullptr, nullptr,
                                          nullptr, attf, kNP, kNP, kNP);
  }
  {
    dim3 g(kM / 128, 3);      // 125 x 3 (cols padded to 384)
    k_mfma_gemm<2><<<g, 256, 0, stream>>>(attf, baf, whead, reg_b, cls_b,
                                          anchors, rp, kK2, kD, kK2);
  }
}